// Round 2
// baseline (152.838 us; speedup 1.0000x reference)
//
#include <hip/hip_runtime.h>
#include <hip/hip_cooperative_groups.h>

namespace cg = cooperative_groups;

#define BATCH   131072
#define NBLK    512     // BATCH / 256  (= 2 blocks per CU on 256 CUs)

// ---------------------------------------------------------------------------
// Fused cooperative kernel: one thread per sample.
//   Phase 1: pool 24x24 -> 16, encode -> 4 angles, 4-qubit circuit in regs,
//            MLP 4->32->4  (pre-BN result stays in registers),
//            per-block partial sums (sum, sumsq per feature) -> d_ws.
//   grid.sync()
//   Phase 2: every block redundantly reduces the 512x8 partials (4 KB, L2),
//            computes BN scale/shift, applies to registers, writes d_out once.
// ---------------------------------------------------------------------------
__global__ __launch_bounds__(256, 2) void qnat_fused(
    const float* __restrict__ x,
    const float* __restrict__ Wenc, const float* __restrict__ benc,
    const float* __restrict__ W1,   const float* __restrict__ b1,
    const float* __restrict__ W2,   const float* __restrict__ b2,
    const float* __restrict__ gamma, const float* __restrict__ beta,
    float* __restrict__ out, float* __restrict__ partials)
{
    // Weight staging in LDS: Wenc[64] | benc[4] | W1[128] | b1[32] | W2[128] | b2[4]
    __shared__ float sW[360];
    __shared__ float red[4][8];
    const int t = threadIdx.x;
    if (t < 64)  sW[t]       = Wenc[t];
    if (t < 4)   sW[64 + t]  = benc[t];
    if (t < 128) sW[68 + t]  = W1[t];
    if (t < 32)  sW[196 + t] = b1[t];
    if (t < 128) sW[228 + t] = W2[t];
    if (t < 4)   sW[356 + t] = b2[t];
    __syncthreads();

    const int s = blockIdx.x * 256 + t;
    const float4* xp = reinterpret_cast<const float4*>(x + (size_t)s * 576);

    // ---- avg_pool2d 6x6: 24x24 -> 4x4 (all indices compile-time static) ----
    float pooled[16];
    #pragma unroll
    for (int pr = 0; pr < 4; ++pr) {
        float a0 = 0.f, a1 = 0.f, a2 = 0.f, a3 = 0.f;
        #pragma unroll
        for (int rr = 0; rr < 6; ++rr) {
            const float4* row = xp + (pr * 6 + rr) * 6;
            float4 va = row[0], vb = row[1], vc = row[2];
            float4 vd = row[3], ve = row[4], vf = row[5];
            a0 += va.x + va.y + va.z + va.w + vb.x + vb.y;   // cols 0..5
            a1 += vb.z + vb.w + vc.x + vc.y + vc.z + vc.w;   // cols 6..11
            a2 += vd.x + vd.y + vd.z + vd.w + ve.x + ve.y;   // cols 12..17
            a3 += ve.z + ve.w + vf.x + vf.y + vf.z + vf.w;   // cols 18..23
        }
        pooled[pr * 4 + 0] = a0 * (1.f / 36.f);
        pooled[pr * 4 + 1] = a1 * (1.f / 36.f);
        pooled[pr * 4 + 2] = a2 * (1.f / 36.f);
        pooled[pr * 4 + 3] = a3 * (1.f / 36.f);
    }

    // ---- encoding: enc = pooled @ Wenc^T + benc; angles -> cos/sin of half ----
    float ch[4], sh[4];
    #pragma unroll
    for (int j = 0; j < 4; ++j) {
        float e = sW[64 + j];
        #pragma unroll
        for (int k = 0; k < 16; ++k) e = fmaf(pooled[k], sW[j * 16 + k], e);
        const float h = 0.5f * e;
        ch[j] = cosf(h);
        sh[j] = sinf(h);
    }

    // ---- 4-qubit statevector, idx = q0*8 + q1*4 + q2*2 + q3 (wire w -> bit 8>>w)
    float re[16], im[16];
    #pragma unroll
    for (int i = 0; i < 16; ++i) { re[i] = 0.f; im[i] = 0.f; }
    re[0] = 1.f;

    // RY(w): [[c,-s],[s,c]]
    #pragma unroll
    for (int w = 0; w < 4; ++w) {
        const int bit = 8 >> w;
        #pragma unroll
        for (int i = 0; i < 16; ++i) if (!(i & bit)) {
            const int j = i | bit;
            const float r0 = re[i], m0 = im[i], r1 = re[j], m1 = im[j];
            re[i] = ch[w] * r0 - sh[w] * r1;  im[i] = ch[w] * m0 - sh[w] * m1;
            re[j] = sh[w] * r0 + ch[w] * r1;  im[j] = sh[w] * m0 + ch[w] * m1;
        }
    }
    // RZ(w): diag(e^{-ih}, e^{+ih})
    #pragma unroll
    for (int w = 0; w < 4; ++w) {
        const int bit = 8 >> w;
        #pragma unroll
        for (int i = 0; i < 16; ++i) {
            const float sg = (i & bit) ? 1.f : -1.f;
            const float r = re[i], m = im[i];
            re[i] = ch[w] * r - sg * sh[w] * m;
            im[i] = ch[w] * m + sg * sh[w] * r;
        }
    }
    // CNOTs on adjacent wires: pure register swaps
    #define SWAP_AMP(a, b) { float tr = re[a]; re[a] = re[b]; re[b] = tr; \
                             float ti = im[a]; im[a] = im[b]; im[b] = ti; }
    // CNOT(0,1): control bit 8, target bit 4
    SWAP_AMP(8, 12)  SWAP_AMP(9, 13)  SWAP_AMP(10, 14) SWAP_AMP(11, 15)
    // CNOT(1,2): control bit 4, target bit 2
    SWAP_AMP(4, 6)   SWAP_AMP(5, 7)   SWAP_AMP(12, 14) SWAP_AMP(13, 15)
    // CNOT(2,3): control bit 2, target bit 1
    SWAP_AMP(2, 3)   SWAP_AMP(6, 7)   SWAP_AMP(10, 11) SWAP_AMP(14, 15)
    #undef SWAP_AMP

    // RX(w): [[c,-is],[-is,c]]
    #pragma unroll
    for (int w = 0; w < 4; ++w) {
        const int bit = 8 >> w;
        #pragma unroll
        for (int i = 0; i < 16; ++i) if (!(i & bit)) {
            const int j = i | bit;
            const float r0 = re[i], m0 = im[i], r1 = re[j], m1 = im[j];
            re[i] = ch[w] * r0 + sh[w] * m1;  im[i] = ch[w] * m0 - sh[w] * r1;
            re[j] = sh[w] * m0 + ch[w] * r1;  im[j] = ch[w] * m1 - sh[w] * r0;
        }
    }

    // ---- PauliZ expectations ----
    float ez[4];
    #pragma unroll
    for (int w = 0; w < 4; ++w) {
        const int bit = 8 >> w;
        float acc = 0.f;
        #pragma unroll
        for (int i = 0; i < 16; ++i) {
            const float p = re[i] * re[i] + im[i] * im[i];
            acc += (i & bit) ? -p : p;
        }
        ez[w] = acc;
    }

    // ---- MLP: h = relu(ez @ W1^T + b1); out = h @ W2^T + b2 ----
    float o0 = sW[356], o1 = sW[357], o2 = sW[358], o3 = sW[359];
    #pragma unroll
    for (int i = 0; i < 32; ++i) {
        float h = sW[196 + i];
        #pragma unroll
        for (int j = 0; j < 4; ++j) h = fmaf(ez[j], sW[68 + i * 4 + j], h);
        h = fmaxf(h, 0.f);
        o0 = fmaf(h, sW[228 +  0 + i], o0);
        o1 = fmaf(h, sW[228 + 32 + i], o1);
        o2 = fmaf(h, sW[228 + 64 + i], o2);
        o3 = fmaf(h, sW[228 + 96 + i], o3);
    }

    // ---- deterministic block reduction of sum / sumsq per feature ----
    {
        float v[8] = { o0, o1, o2, o3, o0 * o0, o1 * o1, o2 * o2, o3 * o3 };
        #pragma unroll
        for (int off = 32; off; off >>= 1) {
            #pragma unroll
            for (int k = 0; k < 8; ++k) v[k] += __shfl_down(v[k], off);
        }
        const int wave = t >> 6, lane = t & 63;
        if (lane == 0) {
            #pragma unroll
            for (int k = 0; k < 8; ++k) red[wave][k] = v[k];
        }
        __syncthreads();
        if (t < 8) {
            partials[blockIdx.x * 8 + t] = red[0][t] + red[1][t] + red[2][t] + red[3][t];
        }
    }

    // ---- grid-wide barrier: all partials visible everywhere after this ----
    cg::this_grid().sync();

    // ---- every block redundantly reduces 512x8 partials (4 KB, L2-hot) ----
    {
        // thread t handles rows 2t and 2t+1 (row = 8 floats = 2 float4s)
        const float4* p4 = reinterpret_cast<const float4*>(partials);
        const float4 a0 = p4[t * 4 + 0], a1 = p4[t * 4 + 1];   // row 2t
        const float4 a2 = p4[t * 4 + 2], a3 = p4[t * 4 + 3];   // row 2t+1
        float v[8] = { a0.x + a2.x, a0.y + a2.y, a0.z + a2.z, a0.w + a2.w,
                       a1.x + a3.x, a1.y + a3.y, a1.z + a3.z, a1.w + a3.w };
        #pragma unroll
        for (int off = 32; off; off >>= 1) {
            #pragma unroll
            for (int k = 0; k < 8; ++k) v[k] += __shfl_down(v[k], off);
        }
        const int wave = t >> 6, lane = t & 63;
        __syncthreads();   // red[] reuse: ensure phase-1 reads are done
        if (lane == 0) {
            #pragma unroll
            for (int k = 0; k < 8; ++k) red[wave][k] = v[k];
        }
        __syncthreads();
    }

    // ---- every thread computes scale/shift (broadcast LDS reads) ----
    float sc[4], sf[4];
    #pragma unroll
    for (int j = 0; j < 4; ++j) {
        const float sum   = red[0][j] + red[1][j] + red[2][j] + red[3][j];
        const float sumsq = red[0][4 + j] + red[1][4 + j] + red[2][4 + j] + red[3][4 + j];
        const float invB  = 1.f / (float)BATCH;
        const float mean  = sum * invB;
        const float var   = sumsq * invB - mean * mean;
        sc[j] = gamma[j] / sqrtf(var + 1e-5f);
        sf[j] = beta[j] - mean * sc[j];
    }

    reinterpret_cast<float4*>(out)[s] = make_float4(
        fmaf(o0, sc[0], sf[0]), fmaf(o1, sc[1], sf[1]),
        fmaf(o2, sc[2], sf[2]), fmaf(o3, sc[3], sf[3]));
}

extern "C" void kernel_launch(void* const* d_in, const int* in_sizes, int n_in,
                              void* d_out, int out_size, void* d_ws, size_t ws_size,
                              hipStream_t stream)
{
    const float* x     = (const float*)d_in[0];
    const float* Wenc  = (const float*)d_in[1];
    const float* benc  = (const float*)d_in[2];
    const float* W1    = (const float*)d_in[3];
    const float* b1    = (const float*)d_in[4];
    const float* W2    = (const float*)d_in[5];
    const float* b2    = (const float*)d_in[6];
    const float* gamma = (const float*)d_in[7];
    const float* beta  = (const float*)d_in[8];

    float* out      = (float*)d_out;
    float* partials = (float*)d_ws;   // 512 * 8 floats

    void* args[] = { (void*)&x, (void*)&Wenc, (void*)&benc, (void*)&W1, (void*)&b1,
                     (void*)&W2, (void*)&b2, (void*)&gamma, (void*)&beta,
                     (void*)&out, (void*)&partials };
    hipLaunchCooperativeKernel((void*)qnat_fused, dim3(NBLK), dim3(256),
                               args, 0, stream);
}

// Round 3
// 99.338 us; speedup vs baseline: 1.5386x; 1.5386x over previous
//
#include <hip/hip_runtime.h>

#define BATCH      131072
#define NBLK_MAIN  2048    // BATCH*4 threads / 256  (8 blocks/CU -> 32 waves/CU)
#define NBLK_BN    512     // BATCH / 256

// ---------------------------------------------------------------------------
// Kernel 1: FOUR threads per sample (lane group k=0..3).
//   Thread k pools rows 6k..6k+5 (576 contiguous bytes), partial-dots the
//   encoding, group shfl-reduce -> all 4 lanes hold the 4 angles; circuit +
//   MLP run redundantly in the group. Lane k stores out[s*4+k] (coalesced)
//   and contributes feature k to the per-block BN partials.
// ---------------------------------------------------------------------------
__global__ __launch_bounds__(256, 8) void qnat_main(
    const float* __restrict__ x,
    const float* __restrict__ Wenc, const float* __restrict__ benc,
    const float* __restrict__ W1,   const float* __restrict__ b1,
    const float* __restrict__ W2,   const float* __restrict__ b2,
    float* __restrict__ out_pre, float* __restrict__ partials)
{
    // Weight staging in LDS: Wenc[64] | benc[4] | W1[128] | b1[32] | W2[128] | b2[4]
    __shared__ float sW[360];
    __shared__ float redS[4][4], redQ[4][4];
    const int t = threadIdx.x;
    if (t < 64)  sW[t]       = Wenc[t];
    if (t < 4)   sW[64 + t]  = benc[t];
    if (t < 128) sW[68 + t]  = W1[t];
    if (t < 32)  sW[196 + t] = b1[t];
    if (t < 128) sW[228 + t] = W2[t];
    if (t < 4)   sW[356 + t] = b2[t];
    __syncthreads();

    const int gid = blockIdx.x * 64 + (t >> 2);   // sample index
    const int k   = t & 3;                        // band / feature index
    const float4* xp = reinterpret_cast<const float4*>(
        x + (size_t)gid * 576 + k * 144);         // rows 6k..6k+5, contiguous

    // ---- avg_pool band pr=k: 6 rows of 24 -> 4 column-block sums ----
    float a0 = 0.f, a1 = 0.f, a2 = 0.f, a3 = 0.f;
    #pragma unroll
    for (int rr = 0; rr < 6; ++rr) {
        const float4* row = xp + rr * 6;
        float4 va = row[0], vb = row[1], vc = row[2];
        float4 vd = row[3], ve = row[4], vf = row[5];
        a0 += va.x + va.y + va.z + va.w + vb.x + vb.y;   // cols 0..5
        a1 += vb.z + vb.w + vc.x + vc.y + vc.z + vc.w;   // cols 6..11
        a2 += vd.x + vd.y + vd.z + vd.w + ve.x + ve.y;   // cols 12..17
        a3 += ve.z + ve.w + vf.x + vf.y + vf.z + vf.w;   // cols 18..23
    }
    const float pk[4] = { a0 * (1.f / 36.f), a1 * (1.f / 36.f),
                          a2 * (1.f / 36.f), a3 * (1.f / 36.f) };

    // ---- encoding: partial dot over this lane's 4 pooled values,
    //      group-reduce so all 4 lanes get enc_j; then cos/sin of half ----
    float ch[4], sh[4];
    #pragma unroll
    for (int j = 0; j < 4; ++j) {
        float e = 0.f;
        #pragma unroll
        for (int c = 0; c < 4; ++c) e = fmaf(pk[c], sW[j * 16 + k * 4 + c], e);
        e += __shfl_xor(e, 1);
        e += __shfl_xor(e, 2);
        const float h = 0.5f * (e + sW[64 + j]);
        ch[j] = cosf(h);
        sh[j] = sinf(h);
    }

    // ---- 4-qubit statevector (redundant in the 4-lane group) ----
    float re[16], im[16];
    #pragma unroll
    for (int i = 0; i < 16; ++i) { re[i] = 0.f; im[i] = 0.f; }
    re[0] = 1.f;

    // RY(w): [[c,-s],[s,c]]
    #pragma unroll
    for (int w = 0; w < 4; ++w) {
        const int bit = 8 >> w;
        #pragma unroll
        for (int i = 0; i < 16; ++i) if (!(i & bit)) {
            const int j = i | bit;
            const float r0 = re[i], m0 = im[i], r1 = re[j], m1 = im[j];
            re[i] = ch[w] * r0 - sh[w] * r1;  im[i] = ch[w] * m0 - sh[w] * m1;
            re[j] = sh[w] * r0 + ch[w] * r1;  im[j] = sh[w] * m0 + ch[w] * m1;
        }
    }
    // RZ(w): diag(e^{-ih}, e^{+ih})
    #pragma unroll
    for (int w = 0; w < 4; ++w) {
        const int bit = 8 >> w;
        #pragma unroll
        for (int i = 0; i < 16; ++i) {
            const float sg = (i & bit) ? 1.f : -1.f;
            const float r = re[i], m = im[i];
            re[i] = ch[w] * r - sg * sh[w] * m;
            im[i] = ch[w] * m + sg * sh[w] * r;
        }
    }
    // CNOTs on adjacent wires: pure register swaps
    #define SWAP_AMP(a, b) { float tr = re[a]; re[a] = re[b]; re[b] = tr; \
                             float ti = im[a]; im[a] = im[b]; im[b] = ti; }
    SWAP_AMP(8, 12)  SWAP_AMP(9, 13)  SWAP_AMP(10, 14) SWAP_AMP(11, 15)
    SWAP_AMP(4, 6)   SWAP_AMP(5, 7)   SWAP_AMP(12, 14) SWAP_AMP(13, 15)
    SWAP_AMP(2, 3)   SWAP_AMP(6, 7)   SWAP_AMP(10, 11) SWAP_AMP(14, 15)
    #undef SWAP_AMP

    // RX(w): [[c,-is],[-is,c]]
    #pragma unroll
    for (int w = 0; w < 4; ++w) {
        const int bit = 8 >> w;
        #pragma unroll
        for (int i = 0; i < 16; ++i) if (!(i & bit)) {
            const int j = i | bit;
            const float r0 = re[i], m0 = im[i], r1 = re[j], m1 = im[j];
            re[i] = ch[w] * r0 + sh[w] * m1;  im[i] = ch[w] * m0 - sh[w] * r1;
            re[j] = sh[w] * m0 + ch[w] * r1;  im[j] = ch[w] * m1 - sh[w] * r0;
        }
    }

    // ---- PauliZ expectations ----
    float ez[4];
    #pragma unroll
    for (int w = 0; w < 4; ++w) {
        const int bit = 8 >> w;
        float acc = 0.f;
        #pragma unroll
        for (int i = 0; i < 16; ++i) {
            const float p = re[i] * re[i] + im[i] * im[i];
            acc += (i & bit) ? -p : p;
        }
        ez[w] = acc;
    }

    // ---- MLP: h = relu(ez @ W1^T + b1); out = h @ W2^T + b2 ----
    float o0 = sW[356], o1 = sW[357], o2 = sW[358], o3 = sW[359];
    #pragma unroll
    for (int i = 0; i < 32; ++i) {
        float h = sW[196 + i];
        #pragma unroll
        for (int j = 0; j < 4; ++j) h = fmaf(ez[j], sW[68 + i * 4 + j], h);
        h = fmaxf(h, 0.f);
        o0 = fmaf(h, sW[228 +  0 + i], o0);
        o1 = fmaf(h, sW[228 + 32 + i], o1);
        o2 = fmaf(h, sW[228 + 64 + i], o2);
        o3 = fmaf(h, sW[228 + 96 + i], o3);
    }

    // lane k of the group owns feature k: coalesced 4B store
    const float ov = (k == 0) ? o0 : (k == 1) ? o1 : (k == 2) ? o2 : o3;
    out_pre[(size_t)blockIdx.x * 256 + t] = ov;

    // ---- BN partials: lanes with same (t&3) sum feature (t&3) ----
    float vs = ov, vq = ov * ov;
    #pragma unroll
    for (int off = 32; off >= 4; off >>= 1) {
        vs += __shfl_down(vs, off);
        vq += __shfl_down(vq, off);
    }
    const int wave = t >> 6, lane = t & 63;
    if (lane < 4) { redS[wave][lane] = vs; redQ[wave][lane] = vq; }
    __syncthreads();
    if (t < 8) {
        const int f = t & 3;
        const float r = (t < 4)
            ? (redS[0][f] + redS[1][f] + redS[2][f] + redS[3][f])
            : (redQ[0][f] + redQ[1][f] + redQ[2][f] + redQ[3][f]);
        partials[blockIdx.x * 8 + t] = r;
    }
}

// ---------------------------------------------------------------------------
// Kernel 2: reduce 2048 block-partials -> scale/shift (8 floats in d_ws).
// ---------------------------------------------------------------------------
__global__ __launch_bounds__(512) void qnat_reduce(
    const float* __restrict__ partials, const float* __restrict__ gamma,
    const float* __restrict__ beta, float* __restrict__ ss)
{
    const int t = threadIdx.x;   // 0..511, four partial rows each
    const float4* p4 = reinterpret_cast<const float4*>(partials);
    float v[8] = { 0.f, 0.f, 0.f, 0.f, 0.f, 0.f, 0.f, 0.f };
    #pragma unroll
    for (int r = 0; r < 4; ++r) {
        const float4 a = p4[t * 8 + r * 2], b = p4[t * 8 + r * 2 + 1];
        v[0] += a.x; v[1] += a.y; v[2] += a.z; v[3] += a.w;
        v[4] += b.x; v[5] += b.y; v[6] += b.z; v[7] += b.w;
    }
    #pragma unroll
    for (int off = 32; off; off >>= 1) {
        #pragma unroll
        for (int kk = 0; kk < 8; ++kk) v[kk] += __shfl_down(v[kk], off);
    }
    __shared__ float red[8][8];
    const int wave = t >> 6, lane = t & 63;
    if (lane == 0) {
        #pragma unroll
        for (int kk = 0; kk < 8; ++kk) red[wave][kk] = v[kk];
    }
    __syncthreads();
    if (t < 4) {
        float sum = 0.f, sumsq = 0.f;
        #pragma unroll
        for (int w = 0; w < 8; ++w) { sum += red[w][t]; sumsq += red[w][4 + t]; }
        const float invB  = 1.f / (float)BATCH;
        const float mean  = sum * invB;
        const float var   = sumsq * invB - mean * mean;
        const float scale = gamma[t] / sqrtf(var + 1e-5f);
        ss[t]     = scale;
        ss[4 + t] = beta[t] - mean * scale;
    }
}

// ---------------------------------------------------------------------------
// Kernel 3: apply BN in place on d_out: out = pre * scale[j] + shift[j].
// ---------------------------------------------------------------------------
__global__ __launch_bounds__(256) void qnat_bn(
    float* __restrict__ io, const float* __restrict__ ss)
{
    __shared__ float s8[8];
    if (threadIdx.x < 8) s8[threadIdx.x] = ss[threadIdx.x];
    __syncthreads();
    const int idx = blockIdx.x * 256 + threadIdx.x;   // one sample (float4) each
    float4* p = reinterpret_cast<float4*>(io);
    float4 v = p[idx];
    v.x = fmaf(v.x, s8[0], s8[4]);
    v.y = fmaf(v.y, s8[1], s8[5]);
    v.z = fmaf(v.z, s8[2], s8[6]);
    v.w = fmaf(v.w, s8[3], s8[7]);
    p[idx] = v;
}

extern "C" void kernel_launch(void* const* d_in, const int* in_sizes, int n_in,
                              void* d_out, int out_size, void* d_ws, size_t ws_size,
                              hipStream_t stream)
{
    const float* x     = (const float*)d_in[0];
    const float* Wenc  = (const float*)d_in[1];
    const float* benc  = (const float*)d_in[2];
    const float* W1    = (const float*)d_in[3];
    const float* b1    = (const float*)d_in[4];
    const float* W2    = (const float*)d_in[5];
    const float* b2    = (const float*)d_in[6];
    const float* gamma = (const float*)d_in[7];
    const float* beta  = (const float*)d_in[8];

    float* out      = (float*)d_out;
    float* partials = (float*)d_ws;                 // 2048 * 8 floats = 64 KB
    float* ss       = partials + NBLK_MAIN * 8;     // 8 floats (scale, shift)

    qnat_main<<<NBLK_MAIN, 256, 0, stream>>>(x, Wenc, benc, W1, b1, W2, b2,
                                             out, partials);
    qnat_reduce<<<1, 512, 0, stream>>>(partials, gamma, beta, ss);
    qnat_bn<<<NBLK_BN, 256, 0, stream>>>(out, ss);
}

// Round 4
// 59.770 us; speedup vs baseline: 2.5571x; 1.6620x over previous
//
#include <hip/hip_runtime.h>

#define BATCH      131072
#define NBLK_MAIN  512     // 256 threads/block, 1 sample/thread
#define NBLK_BN    512

// ---------------------------------------------------------------------------
// Kernel 1: one thread per sample, but WAVE-COALESCED loading.
//   Each wave owns 64 samples. 16 chunks of 4 samples:
//     - 9 x (64 lanes x 16 B = 1 KB) contiguous global loads to regs
//     - ds_write into padded per-sample LDS layout (580-float stride)
//     - 16 lanes/sample pool one 6x6 block each -> 1 pooled value/lane/chunk
//   Redistribute pooled values via LDS so lane l owns sample l's 16 values,
//   then run the validated circuit + MLP + BN-partial code (R1).
// ---------------------------------------------------------------------------
__global__ __launch_bounds__(256, 2) void qnat_main(
    const float* __restrict__ x,
    const float* __restrict__ Wenc, const float* __restrict__ benc,
    const float* __restrict__ W1,   const float* __restrict__ b1,
    const float* __restrict__ W2,   const float* __restrict__ b2,
    float* __restrict__ out_pre, float* __restrict__ partials)
{
    // Weights: Wenc[64] | benc[4] | W1[128] | b1[32] | W2[128] | b2[4]
    __shared__ float sW[360];
    __shared__ __align__(16) float stage[4][2320];  // per-wave: 4 samples x 580 (576+4 pad)
    __shared__ float pbuf[4][1088];                 // per-wave: 64 samples x 17 (16+1 pad)
    __shared__ float redS[4][8];

    const int t = threadIdx.x;
    if (t < 64)  sW[t]       = Wenc[t];
    if (t < 4)   sW[64 + t]  = benc[t];
    if (t < 128) sW[68 + t]  = W1[t];
    if (t < 32)  sW[196 + t] = b1[t];
    if (t < 128) sW[228 + t] = W2[t];
    if (t < 4)   sW[356 + t] = b2[t];
    __syncthreads();

    const int wave = t >> 6, lane = t & 63;
    const int sampleBase = blockIdx.x * 256 + wave * 64;   // this wave's 64 samples
    float* st = stage[wave];
    float* pb = pbuf[wave];

    // pooling geometry: 16 lanes per sample; slot = pr*4+pc (6x6 block)
    const int s_loc = lane >> 4;          // sample-within-chunk 0..3
    const int slot  = lane & 15;          // pooled cell index
    const int spr   = slot >> 2, spc = slot & 3;
    const int rdOff = s_loc * 580 + spr * 144 + spc * 6;

    const float4* xg = reinterpret_cast<const float4*>(x);
    const unsigned gbase = (unsigned)sampleBase * 144u;    // float4 index of wave's region

    float pv[16];
    #pragma unroll
    for (int c = 0; c < 16; ++c) {
        // ---- 9 wave-contiguous 1-KB loads (chunk = 4 samples = 576 float4) ----
        float4 v[9];
        #pragma unroll
        for (int i = 0; i < 9; ++i)
            v[i] = xg[gbase + (unsigned)c * 576u + (unsigned)i * 64u + (unsigned)lane];
        // ---- scatter to padded LDS layout ----
        #pragma unroll
        for (int i = 0; i < 9; ++i) {
            const int g = i * 64 + lane;        // 0..575 float4 within chunk
            const int s = g / 144;              // sample 0..3
            const int q = g - s * 144;          // float4 within sample
            *reinterpret_cast<float4*>(&st[s * 580 + q * 4]) = v[i];
        }
        // ---- pool this lane's 6x6 block ----
        float acc = 0.f;
        #pragma unroll
        for (int r = 0; r < 6; ++r) {
            const float2 a  = *reinterpret_cast<const float2*>(&st[rdOff + r * 24 + 0]);
            const float2 bb = *reinterpret_cast<const float2*>(&st[rdOff + r * 24 + 2]);
            const float2 cc = *reinterpret_cast<const float2*>(&st[rdOff + r * 24 + 4]);
            acc += a.x + a.y + bb.x + bb.y + cc.x + cc.y;
        }
        pv[c] = acc * (1.f / 36.f);
    }

    // ---- redistribute: lane l ends up owning sample l's 16 pooled values ----
    #pragma unroll
    for (int c = 0; c < 16; ++c)
        pb[(c * 4 + s_loc) * 17 + slot] = pv[c];
    float pooled[16];
    #pragma unroll
    for (int q = 0; q < 16; ++q)
        pooled[q] = pb[lane * 17 + q];

    // ---- encoding: enc = pooled @ Wenc^T + benc; angles -> cos/sin of half ----
    float ch[4], sh[4];
    #pragma unroll
    for (int j = 0; j < 4; ++j) {
        float e = sW[64 + j];
        #pragma unroll
        for (int k = 0; k < 16; ++k) e = fmaf(pooled[k], sW[j * 16 + k], e);
        const float h = 0.5f * e;
        ch[j] = cosf(h);
        sh[j] = sinf(h);
    }

    // ---- 4-qubit statevector, idx bit for wire w is 8>>w ----
    float re[16], im[16];
    #pragma unroll
    for (int i = 0; i < 16; ++i) { re[i] = 0.f; im[i] = 0.f; }
    re[0] = 1.f;

    // RY(w): [[c,-s],[s,c]]
    #pragma unroll
    for (int w = 0; w < 4; ++w) {
        const int bit = 8 >> w;
        #pragma unroll
        for (int i = 0; i < 16; ++i) if (!(i & bit)) {
            const int jj = i | bit;
            const float r0 = re[i], m0 = im[i], r1 = re[jj], m1 = im[jj];
            re[i]  = ch[w] * r0 - sh[w] * r1;  im[i]  = ch[w] * m0 - sh[w] * m1;
            re[jj] = sh[w] * r0 + ch[w] * r1;  im[jj] = sh[w] * m0 + ch[w] * m1;
        }
    }
    // RZ(w): diag(e^{-ih}, e^{+ih})
    #pragma unroll
    for (int w = 0; w < 4; ++w) {
        const int bit = 8 >> w;
        #pragma unroll
        for (int i = 0; i < 16; ++i) {
            const float sg = (i & bit) ? 1.f : -1.f;
            const float r = re[i], m = im[i];
            re[i] = ch[w] * r - sg * sh[w] * m;
            im[i] = ch[w] * m + sg * sh[w] * r;
        }
    }
    // CNOTs on adjacent wires: pure register swaps
    #define SWAP_AMP(a, b) { float tr = re[a]; re[a] = re[b]; re[b] = tr; \
                             float ti = im[a]; im[a] = im[b]; im[b] = ti; }
    SWAP_AMP(8, 12)  SWAP_AMP(9, 13)  SWAP_AMP(10, 14) SWAP_AMP(11, 15)
    SWAP_AMP(4, 6)   SWAP_AMP(5, 7)   SWAP_AMP(12, 14) SWAP_AMP(13, 15)
    SWAP_AMP(2, 3)   SWAP_AMP(6, 7)   SWAP_AMP(10, 11) SWAP_AMP(14, 15)
    #undef SWAP_AMP

    // RX(w): [[c,-is],[-is,c]]
    #pragma unroll
    for (int w = 0; w < 4; ++w) {
        const int bit = 8 >> w;
        #pragma unroll
        for (int i = 0; i < 16; ++i) if (!(i & bit)) {
            const int jj = i | bit;
            const float r0 = re[i], m0 = im[i], r1 = re[jj], m1 = im[jj];
            re[i]  = ch[w] * r0 + sh[w] * m1;  im[i]  = ch[w] * m0 - sh[w] * r1;
            re[jj] = sh[w] * m0 + ch[w] * r1;  im[jj] = ch[w] * m1 - sh[w] * r0;
        }
    }

    // ---- PauliZ expectations ----
    float ez[4];
    #pragma unroll
    for (int w = 0; w < 4; ++w) {
        const int bit = 8 >> w;
        float acc = 0.f;
        #pragma unroll
        for (int i = 0; i < 16; ++i) {
            const float p = re[i] * re[i] + im[i] * im[i];
            acc += (i & bit) ? -p : p;
        }
        ez[w] = acc;
    }

    // ---- MLP: h = relu(ez @ W1^T + b1); out = h @ W2^T + b2 ----
    float o0 = sW[356], o1 = sW[357], o2 = sW[358], o3 = sW[359];
    #pragma unroll
    for (int i = 0; i < 32; ++i) {
        float h = sW[196 + i];
        #pragma unroll
        for (int j = 0; j < 4; ++j) h = fmaf(ez[j], sW[68 + i * 4 + j], h);
        h = fmaxf(h, 0.f);
        o0 = fmaf(h, sW[228 +  0 + i], o0);
        o1 = fmaf(h, sW[228 + 32 + i], o1);
        o2 = fmaf(h, sW[228 + 64 + i], o2);
        o3 = fmaf(h, sW[228 + 96 + i], o3);
    }

    // sample index of this thread = blockIdx.x*256 + t (wave*64 + lane)
    reinterpret_cast<float4*>(out_pre)[blockIdx.x * 256 + t] =
        make_float4(o0, o1, o2, o3);

    // ---- deterministic block reduction of sum / sumsq per feature ----
    {
        float v8[8] = { o0, o1, o2, o3, o0 * o0, o1 * o1, o2 * o2, o3 * o3 };
        #pragma unroll
        for (int off = 32; off; off >>= 1) {
            #pragma unroll
            for (int k = 0; k < 8; ++k) v8[k] += __shfl_down(v8[k], off);
        }
        if (lane == 0) {
            #pragma unroll
            for (int k = 0; k < 8; ++k) redS[wave][k] = v8[k];
        }
        __syncthreads();
        if (t < 8) {
            partials[blockIdx.x * 8 + t] =
                redS[0][t] + redS[1][t] + redS[2][t] + redS[3][t];
        }
    }
}

// ---------------------------------------------------------------------------
// Kernel 2: reduce 512 block-partials -> scale/shift (8 floats in d_ws).
// ---------------------------------------------------------------------------
__global__ __launch_bounds__(512) void qnat_reduce(
    const float* __restrict__ partials, const float* __restrict__ gamma,
    const float* __restrict__ beta, float* __restrict__ ss)
{
    const int t = threadIdx.x;   // 0..511, one partial row each
    const float4* p4 = reinterpret_cast<const float4*>(partials);
    const float4 a = p4[t * 2], b = p4[t * 2 + 1];
    float v[8] = { a.x, a.y, a.z, a.w, b.x, b.y, b.z, b.w };
    #pragma unroll
    for (int off = 32; off; off >>= 1) {
        #pragma unroll
        for (int k = 0; k < 8; ++k) v[k] += __shfl_down(v[k], off);
    }
    __shared__ float red[8][8];
    const int wave = t >> 6, lane = t & 63;
    if (lane == 0) {
        #pragma unroll
        for (int k = 0; k < 8; ++k) red[wave][k] = v[k];
    }
    __syncthreads();
    if (t < 4) {
        float sum = 0.f, sumsq = 0.f;
        #pragma unroll
        for (int w = 0; w < 8; ++w) { sum += red[w][t]; sumsq += red[w][4 + t]; }
        const float invB  = 1.f / (float)BATCH;
        const float mean  = sum * invB;
        const float var   = sumsq * invB - mean * mean;
        const float scale = gamma[t] / sqrtf(var + 1e-5f);
        ss[t]     = scale;
        ss[4 + t] = beta[t] - mean * scale;
    }
}

// ---------------------------------------------------------------------------
// Kernel 3: apply BN in place on d_out: out = pre * scale[j] + shift[j].
// ---------------------------------------------------------------------------
__global__ __launch_bounds__(256) void qnat_bn(
    float* __restrict__ io, const float* __restrict__ ss)
{
    __shared__ float s8[8];
    if (threadIdx.x < 8) s8[threadIdx.x] = ss[threadIdx.x];
    __syncthreads();
    const int idx = blockIdx.x * 256 + threadIdx.x;   // one sample (float4) each
    float4* p = reinterpret_cast<float4*>(io);
    float4 v = p[idx];
    v.x = fmaf(v.x, s8[0], s8[4]);
    v.y = fmaf(v.y, s8[1], s8[5]);
    v.z = fmaf(v.z, s8[2], s8[6]);
    v.w = fmaf(v.w, s8[3], s8[7]);
    p[idx] = v;
}

extern "C" void kernel_launch(void* const* d_in, const int* in_sizes, int n_in,
                              void* d_out, int out_size, void* d_ws, size_t ws_size,
                              hipStream_t stream)
{
    const float* x     = (const float*)d_in[0];
    const float* Wenc  = (const float*)d_in[1];
    const float* benc  = (const float*)d_in[2];
    const float* W1    = (const float*)d_in[3];
    const float* b1    = (const float*)d_in[4];
    const float* W2    = (const float*)d_in[5];
    const float* b2    = (const float*)d_in[6];
    const float* gamma = (const float*)d_in[7];
    const float* beta  = (const float*)d_in[8];

    float* out      = (float*)d_out;
    float* partials = (float*)d_ws;                 // 512 * 8 floats
    float* ss       = partials + NBLK_MAIN * 8;     // 8 floats (scale, shift)

    qnat_main<<<NBLK_MAIN, 256, 0, stream>>>(x, Wenc, benc, W1, b1, W2, b2,
                                             out, partials);
    qnat_reduce<<<1, 512, 0, stream>>>(partials, gamma, beta, ss);
    qnat_bn<<<NBLK_BN, 256, 0, stream>>>(out, ss);
}